// Round 1
// baseline (282.917 us; speedup 1.0000x reference)
//
#include <hip/hip_runtime.h>

#define BATCH 512
#define NUM_CLASSES 100000
#define NVEC (NUM_CLASSES / 4)     // 25000 float4 per row
#define CHUNKS 4
#define CVEC (NVEC / CHUNKS)       // 6250 float4 per chunk
#define BLOCK 256                  // chunk kernel block
#define FBLOCK 512                 // final kernel block (== BATCH)

// cos(0.5), sin(0.5) as literals (margin = 0.5)
#define COS_M 0.8775825618903728f
#define SIN_M 0.479425538604203f
#define SHIFT 64.0f                // fixed logsumexp shift; logits bounded by 63.36

__device__ __forceinline__ float wave_reduce(float v) {
    #pragma unroll
    for (int off = 32; off > 0; off >>= 1)
        v += __shfl_down(v, off, 64);
    return v;
}

// One block per (row, chunk): plain sum of exp(64*c - SHIFT) over the chunk.
// 2048 blocks x 256 threads = 32 waves/CU (full occupancy); unroll-by-2 with
// dual accumulators keeps 2 independent 1KB wave-loads in flight.
__global__ __launch_bounds__(BLOCK)
void arc_chunk_sum(const float* __restrict__ costh,
                   float*       __restrict__ partial) {
    const int row   = blockIdx.x >> 2;            // / CHUNKS
    const int chunk = blockIdx.x & (CHUNKS - 1);
    const float4* vp = (const float4*)(costh + (size_t)row * NUM_CLASSES)
                       + chunk * CVEC;

    float s0 = 0.0f, s1 = 0.0f;
    int i = threadIdx.x;
    // CVEC = 6250 = 24*256 + 106: pair loop + at most one leftover per thread
    for (; i + BLOCK < CVEC; i += 2 * BLOCK) {
        float4 a = vp[i];
        float4 b = vp[i + BLOCK];
        s0 += __expf(fmaf(64.0f, a.x, -SHIFT));
        s1 += __expf(fmaf(64.0f, a.y, -SHIFT));
        s0 += __expf(fmaf(64.0f, a.z, -SHIFT));
        s1 += __expf(fmaf(64.0f, a.w, -SHIFT));
        s0 += __expf(fmaf(64.0f, b.x, -SHIFT));
        s1 += __expf(fmaf(64.0f, b.y, -SHIFT));
        s0 += __expf(fmaf(64.0f, b.z, -SHIFT));
        s1 += __expf(fmaf(64.0f, b.w, -SHIFT));
    }
    if (i < CVEC) {
        float4 a = vp[i];
        s0 += __expf(fmaf(64.0f, a.x, -SHIFT));
        s1 += __expf(fmaf(64.0f, a.y, -SHIFT));
        s0 += __expf(fmaf(64.0f, a.z, -SHIFT));
        s1 += __expf(fmaf(64.0f, a.w, -SHIFT));
    }

    float v = wave_reduce(s0 + s1);
    __shared__ float smem[BLOCK / 64];
    const int lane = threadIdx.x & 63;
    const int wid  = threadIdx.x >> 6;
    if (lane == 0) smem[wid] = v;
    __syncthreads();
    if (threadIdx.x == 0)
        partial[blockIdx.x] = (smem[0] + smem[1]) + (smem[2] + smem[3]);
}

// One thread per row: combine the 4 chunk partials (float4 read), swap the raw
// label logit for the margin-shifted one, form lse - target, then mean-reduce.
__global__ __launch_bounds__(FBLOCK)
void arc_final(const float* __restrict__ costh,
               const int*   __restrict__ label,
               const float* __restrict__ partial,
               float*       __restrict__ out) {
    const int r = threadIdx.x;                    // FBLOCK == BATCH == 512
    const float4 p = ((const float4*)partial)[r];
    const int lab = label[r];
    const float c_y = costh[(size_t)r * NUM_CLASSES + lab];

    float tot = (p.x + p.y) + (p.z + p.w);
    // cos(acos(c) + m) = c*cos(m) - sqrt(1-c^2)*sin(m)
    const float t = 64.0f * (c_y * COS_M -
                             sqrtf(fmaxf(0.0f, 1.0f - c_y * c_y)) * SIN_M);
    const float s = tot - __expf(fmaf(64.0f, c_y, -SHIFT)) + __expf(t - SHIFT);
    float v = (SHIFT + logf(s)) - t;              // lse - target_logit

    v = wave_reduce(v);
    __shared__ float smem[FBLOCK / 64];
    const int lane = threadIdx.x & 63;
    const int wid  = threadIdx.x >> 6;
    if (lane == 0) smem[wid] = v;
    __syncthreads();
    if (threadIdx.x == 0) {
        float tv = 0.0f;
        #pragma unroll
        for (int w = 0; w < FBLOCK / 64; ++w) tv += smem[w];
        out[0] = tv * (1.0f / (float)BATCH);
    }
}

extern "C" void kernel_launch(void* const* d_in, const int* in_sizes, int n_in,
                              void* d_out, int out_size, void* d_ws, size_t ws_size,
                              hipStream_t stream) {
    const float* costh = (const float*)d_in[0];
    const int*   label = (const int*)d_in[1];
    float* out = (float*)d_out;
    float* partial = (float*)d_ws;   // BATCH*CHUNKS = 2048 floats (8 KB)

    arc_chunk_sum<<<BATCH * CHUNKS, BLOCK, 0, stream>>>(costh, partial);
    arc_final<<<1, FBLOCK, 0, stream>>>(costh, label, partial, out);
}